// Round 1
// baseline (203.657 us; speedup 1.0000x reference)
//
#include <hip/hip_runtime.h>
#include <math.h>

#define BATCH 8
#define HH 512
#define WW 512
#define IMG (HH * WW)
#define NTOT (BATCH * IMG)
#define FLAGBIT 0x40000000
#define IDXMASK 0x3FFFFFFF
#define THRESH 0.5f

// ---------- union-find helpers (Playne-Stephens style, min-root) ----------

__device__ __forceinline__ int findroot(const int* p, int x) {
    int px;
    while ((px = p[x]) != x) x = px;
    return x;
}

__device__ __forceinline__ void unite(int* p, int a, int b) {
    bool done = false;
    do {
        a = findroot(p, a);
        b = findroot(p, b);
        if (a > b) {
            int old = atomicMin(&p[a], b);
            done = (old == a);
            a = old;
        } else if (b > a) {
            int old = atomicMin(&p[b], a);
            done = (old == b);
            b = old;
        } else {
            done = true;
        }
    } while (!done);
}

// ---------- kernels ----------

__global__ void k_init(const float* __restrict__ preds, const float* __restrict__ targets,
                       int* __restrict__ pP, int* __restrict__ pT) {
    int n = blockIdx.x * blockDim.x + threadIdx.x;
    if (n >= NTOT) return;
    pP[n] = (preds[n] > THRESH) ? n : -1;
    pT[n] = (targets[n] != 0.0f) ? n : -1;
}

__global__ void k_merge(int* __restrict__ pP, int* __restrict__ pT) {
    int n = blockIdx.x * blockDim.x + threadIdx.x;
    if (n >= NTOT) return;
    int pix = n & (IMG - 1);
    int col = pix & (WW - 1);
    int row = pix >> 9;
    bool hasR = (col < WW - 1);
    bool hasD = (row < HH - 1);
    if (pP[n] >= 0) {
        if (hasR && pP[n + 1] >= 0) unite(pP, n, n + 1);
        if (hasD && pP[n + WW] >= 0) unite(pP, n, n + WW);
    }
    if (pT[n] >= 0) {
        if (hasR && pT[n + 1] >= 0) unite(pT, n, n + 1);
        if (hasD && pT[n + WW] >= 0) unite(pT, n, n + WW);
    }
}

__global__ void k_flatten(int* __restrict__ pP, int* __restrict__ pT) {
    int n = blockIdx.x * blockDim.x + threadIdx.x;
    if (n >= NTOT) return;
    if (pP[n] >= 0) pP[n] = findroot(pP, n);
    if (pT[n] >= 0) pT[n] = findroot(pT, n);
}

__global__ void k_mark(const float* __restrict__ preds, const float* __restrict__ targets,
                       int* __restrict__ pP, int* __restrict__ pT) {
    int n = blockIdx.x * blockDim.x + threadIdx.x;
    if (n >= NTOT) return;
    bool fp = preds[n] > THRESH;
    bool ft = targets[n] != 0.0f;
    if (ft && !fp) {  // target fg not covered by pred -> flag target component
        int r = pT[n] & IDXMASK;
        atomicOr(&pT[r], FLAGBIT);
    }
    if (fp && !ft) {  // pred fg not covered by target -> flag pred component
        int r = pP[n] & IDXMASK;
        atomicOr(&pP[r], FLAGBIT);
    }
}

__device__ __forceinline__ float softplusf(float z) {
    // stable log(1 + e^z)
    return fmaxf(z, 0.0f) + log1pf(expf(-fabsf(z)));
}

__device__ __forceinline__ float block_reduce_sum(float v, float* smem4) {
    for (int off = 32; off > 0; off >>= 1) v += __shfl_down(v, off, 64);
    int lane = threadIdx.x & 63, wid = threadIdx.x >> 6;
    if (lane == 0) smem4[wid] = v;
    __syncthreads();
    return smem4[0] + smem4[1] + smem4[2] + smem4[3];
}

__global__ void k_gather(const float* __restrict__ preds, const float* __restrict__ targets,
                         const int* __restrict__ pP, const int* __restrict__ pT,
                         float* __restrict__ partial) {
    int n = blockIdx.x * blockDim.x + threadIdx.x;
    float contrib = 0.0f;
    if (n < NTOT) {
        float x = preds[n];
        float t = targets[n];
        // BCE with logits: t*softplus(-x) + (1-t)*softplus(x)
        float loss = t * softplusf(-x) + (1.0f - t) * softplusf(x);
        bool fp = x > THRESH;
        bool ft = t != 0.0f;
        float m = 0.0f;
        if (ft) {
            int r = pT[n] & IDXMASK;
            if (pT[r] & FLAGBIT) m += 0.5f;  // BETA * neg
        }
        if (fp) {
            int r = pP[n] & IDXMASK;
            if (pP[r] & FLAGBIT) m += 0.5f;  // (1-BETA) * pos
        }
        // (1-ALPHA)*loss + ALPHA*m*loss with ALPHA=0.5
        contrib = (0.5f + 0.5f * m) * loss;
    }
    __shared__ float smem4[4];
    float s = block_reduce_sum(contrib, smem4);
    if (threadIdx.x == 0) partial[blockIdx.x] = s;
}

__global__ void k_final(const float* __restrict__ partial, int nparts, float* __restrict__ out) {
    float s = 0.0f;
    for (int i = threadIdx.x; i < nparts; i += 256) s += partial[i];
    __shared__ float smem4[4];
    float tot = block_reduce_sum(s, smem4);
    if (threadIdx.x == 0) out[0] = tot / (float)NTOT;
}

// ---------- launch ----------

extern "C" void kernel_launch(void* const* d_in, const int* in_sizes, int n_in,
                              void* d_out, int out_size, void* d_ws, size_t ws_size,
                              hipStream_t stream) {
    const float* preds = (const float*)d_in[0];
    const float* targets = (const float*)d_in[1];

    int* pP = (int*)d_ws;           // NTOT ints (8 MB)
    int* pT = pP + NTOT;            // NTOT ints (8 MB)
    float* partial = (float*)(pT + NTOT);  // nblocks floats (32 KB)
    float* out = (float*)d_out;

    const int block = 256;
    const int nblocks = (NTOT + block - 1) / block;  // 8192

    k_init<<<nblocks, block, 0, stream>>>(preds, targets, pP, pT);
    k_merge<<<nblocks, block, 0, stream>>>(pP, pT);
    k_flatten<<<nblocks, block, 0, stream>>>(pP, pT);
    k_mark<<<nblocks, block, 0, stream>>>(preds, targets, pP, pT);
    k_gather<<<nblocks, block, 0, stream>>>(preds, targets, pP, pT, partial);
    k_final<<<1, 256, 0, stream>>>(partial, nblocks, out);
}